// Round 6
// baseline (245.567 us; speedup 1.0000x reference)
//
#include <hip/hip_runtime.h>
#include <hip/hip_bf16.h>
#include <stdint.h>

typedef __hip_bfloat16 bf16;
typedef __attribute__((ext_vector_type(8))) short short8;   // 8 bf16 = 4 VGPRs (MFMA A/B frag)
typedef __attribute__((ext_vector_type(4))) float floatx4;  // 16x16 MFMA C/D frag

#define AS1(p) ((const __attribute__((address_space(1))) void*)(p))
#define AS3(p) ((__attribute__((address_space(3))) void*)(p))

#define M_DIM 4096
#define H_DIM 1024

// fp32 -> bf16 bits, round-to-nearest-even (inputs are finite)
__device__ __forceinline__ unsigned short f2bf(float f) {
    uint32_t u = __float_as_uint(f);
    uint32_t r = (u + 0x7FFFu + ((u >> 16) & 1u)) >> 16;
    return (unsigned short)r;
}
__device__ __forceinline__ float fast_sigmoid(float v) {
    return 1.0f / (1.0f + __expf(-v));
}
__device__ __forceinline__ float fast_tanh(float v) {
    return 2.0f / (1.0f + __expf(-2.0f * v)) - 1.0f;
}

// ---------------------------------------------------------------------------
// Kernel 1: PACK fp32 -> bf16 1KB chunks in 16x16x32-fragment lane order:
// chunk = [4 kg][16 row][8 bf16]; lane l holds bytes l*16 (row=l&15, kg=l>>4).
// Unified KT in [0,64): KT<32 -> x / Wx (k = KT*32..), KT>=32 -> h / Wh.
// Chunk map (32768 x 1KB = 32MB):
//   A (W<16384):  W = mx*512 + KT*8 + ch     (mx<32: 128-row panel, ch<8:
//                 16-row group); row = mx*128 + ch*16 + (l&15)
//   B (W>=16384): W-16384 = ny*512 + c*256 + KT*4 + g   (ny<32: 32-col panel,
//                 c<2: 16-col half, g: gate); wrow = ny*32 + c*16 + (l&15)
// GEMM reads A chunks via global_load_lds (base + lane*16, contiguous) and
// B chunks DIRECTLY into VGPRs (fragment == 16B/lane in lane order).
__global__ __launch_bounds__(256)
void pack_bf16(const float* __restrict__ x, const float* __restrict__ h,
               const float* Wxf, const float* Wxi, const float* Wxo, const float* Wxc,
               const float* Whf, const float* Whi, const float* Who, const float* Whc,
               unsigned short* __restrict__ ws)
{
    const int w = threadIdx.x >> 6;
    const int l = threadIdx.x & 63;
    const uint32_t W = blockIdx.x * 4u + (uint32_t)w;   // chunk id [0, 32768)

    const uint32_t kg = (uint32_t)l >> 4;    // k-group of 8
    const uint32_t rr = (uint32_t)l & 15u;   // row/col within fragment

    const float* src;
    uint32_t row, ktl;
    if (W < 16384u) {                    // A-chunks (x / h)
        const uint32_t ch = W & 7u;
        const uint32_t KT = (W >> 3) & 63u;
        const uint32_t mx = W >> 9;
        src = (KT < 32u) ? x : h;
        ktl = KT & 31u;
        row = mx * 128u + ch * 16u + rr;
    } else {                             // B-chunks (Wx_g / Wh_g)
        const uint32_t V  = W - 16384u;
        const uint32_t g  = V & 3u;
        const uint32_t KT = (V >> 2) & 63u;
        const uint32_t cc = (V >> 8) & 1u;
        const uint32_t ny = V >> 9;
        if (KT < 32u)
            src = (g == 0) ? Wxf : (g == 1) ? Wxi : (g == 2) ? Wxo : Wxc;
        else
            src = (g == 0) ? Whf : (g == 1) ? Whi : (g == 2) ? Who : Whc;
        ktl = KT & 31u;
        row = ny * 32u + cc * 16u + rr;
    }
    const float* s = src + (size_t)row * 1024u + ktl * 32u + kg * 8u;
    const float4 v0 = *(const float4*)s;
    const float4 v1 = *(const float4*)(s + 4);
    short8 pk;
    pk[0] = (short)f2bf(v0.x); pk[1] = (short)f2bf(v0.y);
    pk[2] = (short)f2bf(v0.z); pk[3] = (short)f2bf(v0.w);
    pk[4] = (short)f2bf(v1.x); pk[5] = (short)f2bf(v1.y);
    pk[6] = (short)f2bf(v1.z); pk[7] = (short)f2bf(v1.w);
    *(short8*)(ws + (size_t)W * 512u + (uint32_t)l * 8u) = pk;
}

// ---------------------------------------------------------------------------
// Kernel 2: fused 4-gate GEMM + LSTM pointwise.  B-DIRECT structure:
//  - only A staged in LDS (3-stage ring x 8KB = 24KB); B fragments loaded
//    straight from packed global into VGPRs (double-buffered, 1 K-step ahead)
//    -> LDS pipe (previous binding resource at ~50-65us) drops below the
//    MFMA floor; matrix pipe becomes the critical path.
//  - 16x16x32 MFMA, balanced 4x4 reuse (4 gates x 4 m-tiles), exchange-free
//    epilogue (all gates wave-local).
//  - 256-thread blocks (4 waves = 2M x 2N), tile 128 rows x 4g x 32 cols,
//    grid 1024 = 32 mx x 32 ny; XCD swizzle keeps one ny-set per XCD so B
//    stays L2-resident.
//  - ONE barrier per K-step, counted vmcnt(2): retires A(kt)+B(kt), keeps
//    A(kt+1) prefetch in flight; lgkmcnt(0) at the barrier (stage-ring WAR
//    fix) + sched_barrier(0) (rule #18).
#define GLL(srcp, dstp) __builtin_amdgcn_global_load_lds(AS1(srcp), AS3(dstp), 16, 0, 0)
#define WAITB(N) do {                                                          \
    asm volatile("s_waitcnt vmcnt(" #N ") lgkmcnt(0)\ns_barrier" ::: "memory");\
    __builtin_amdgcn_sched_barrier(0);                                         \
} while (0)

#define MFMA16(a, b, c) __builtin_amdgcn_mfma_f32_16x16x32_bf16((a), (b), (c), 0, 0, 0)

#define ISSUE_A(SL) do {                                                       \
    GLL(pA0, lds + (SL)*8192 + loffA);                                         \
    GLL(pA1, lds + (SL)*8192 + loffA + 1024);                                  \
    pA0 += 4096; pA1 += 4096;                                                  \
} while (0)

#define ISSUE_B(BB) do {                                                       \
    bb##BB##0 = *(const short8*)(pB);                                          \
    bb##BB##1 = *(const short8*)(pB + 512);                                    \
    bb##BB##2 = *(const short8*)(pB + 1024);                                   \
    bb##BB##3 = *(const short8*)(pB + 1536);                                   \
    pB += 2048;                                                                \
} while (0)

#define COMPUTE(SC, BB) do {                                                   \
    const short8 a0_ = *(const short8*)(ldsA + (SC)*8192 + 0);                 \
    const short8 a1_ = *(const short8*)(ldsA + (SC)*8192 + 1024);              \
    const short8 a2_ = *(const short8*)(ldsA + (SC)*8192 + 2048);              \
    const short8 a3_ = *(const short8*)(ldsA + (SC)*8192 + 3072);              \
    acc[0][0] = MFMA16(a0_, bb##BB##0, acc[0][0]);                             \
    acc[0][1] = MFMA16(a1_, bb##BB##0, acc[0][1]);                             \
    acc[0][2] = MFMA16(a2_, bb##BB##0, acc[0][2]);                             \
    acc[0][3] = MFMA16(a3_, bb##BB##0, acc[0][3]);                             \
    acc[1][0] = MFMA16(a0_, bb##BB##1, acc[1][0]);                             \
    acc[1][1] = MFMA16(a1_, bb##BB##1, acc[1][1]);                             \
    acc[1][2] = MFMA16(a2_, bb##BB##1, acc[1][2]);                             \
    acc[1][3] = MFMA16(a3_, bb##BB##1, acc[1][3]);                             \
    acc[2][0] = MFMA16(a0_, bb##BB##2, acc[2][0]);                             \
    acc[2][1] = MFMA16(a1_, bb##BB##2, acc[2][1]);                             \
    acc[2][2] = MFMA16(a2_, bb##BB##2, acc[2][2]);                             \
    acc[2][3] = MFMA16(a3_, bb##BB##2, acc[2][3]);                             \
    acc[3][0] = MFMA16(a0_, bb##BB##3, acc[3][0]);                             \
    acc[3][1] = MFMA16(a1_, bb##BB##3, acc[3][1]);                             \
    acc[3][2] = MFMA16(a2_, bb##BB##3, acc[3][2]);                             \
    acc[3][3] = MFMA16(a3_, bb##BB##3, acc[3][3]);                             \
} while (0)

// ITER(kt): wait(A(kt),B(kt)) ; issue B(kt+1)->buf NXT ; issue A(kt+2)->SL ;
// compute(kt) from stage SC / buf CUR.
#define ITER(SC, SL, CUR, NXT) do {                                            \
    WAITB(2);                                                                  \
    ISSUE_B(NXT);                                                              \
    ISSUE_A(SL);                                                               \
    COMPUTE(SC, CUR);                                                          \
} while (0)

__global__ __launch_bounds__(256, 2)
void lstm_fused_kernel(const unsigned short* __restrict__ ws,
                       const float* __restrict__ c,
                       const float* __restrict__ bxf, const float* __restrict__ bhf,
                       const float* __restrict__ bxi, const float* __restrict__ bhi,
                       const float* __restrict__ bxo, const float* __restrict__ bho,
                       const float* __restrict__ bxc, const float* __restrict__ bhc,
                       float* __restrict__ out)
{
    __shared__ __align__(16) char lds[3 * 8192];   // A ring: 3 stages x 8KB

    const int tid  = threadIdx.x;
    const int w    = tid >> 6;     // 0..3
    const int lane = tid & 63;

    // XCD swizzle: 1024 blocks, 8 XCDs, 128 blocks/XCD = 4 ny-panels x 32 mx.
    // B (512KB/panel) stays L2-resident per XCD; A streams via L3.
    const int bid  = blockIdx.x;
    const int wgid = (bid & 7) * 128 + (bid >> 3);
    const int ny  = wgid >> 5;          // [0,32) 32-col panel
    const int mx  = wgid & 31;          // [0,32) 128-row panel
    const int bm0 = mx * 128;
    const int bn0 = ny * 32;

    const int wM = w >> 1;         // M-half (64 rows)
    const int wN = w & 1;          // 16-col half of the 32-col panel

    // A staging: 8 chunks/stage; wave w DMAs ch = 2w, 2w+1.
    const unsigned short* pA0 = ws + ((uint32_t)mx * 512u + (uint32_t)w * 2u) * 512u
                                   + (uint32_t)lane * 8u;
    const unsigned short* pA1 = pA0 + 512u;
    const uint32_t loffA = (uint32_t)w * 2048u;

    // B direct: window (ny, wN) = 256 chunks [kt][g]; 4 chunks (4KB) per K-step.
    const unsigned short* pB = ws + 8388608u
                                  + ((uint32_t)(ny * 2 + wN)) * 131072u
                                  + (uint32_t)lane * 8u;

    // fragment base for A reads: chunk (wM*4 + mt) -> wM*4096 + mt*1024
    const char* ldsA = lds + (uint32_t)wM * 4096u + (uint32_t)lane * 16u;

    short8 bb00, bb01, bb02, bb03;   // B double-buffer, set 0 (even kt)
    short8 bb10, bb11, bb12, bb13;   // set 1 (odd kt)

    floatx4 acc[4][4];   // [gate][m-tile] = 64 fp32/lane
#pragma unroll
    for (int g = 0; g < 4; ++g)
#pragma unroll
        for (int mt = 0; mt < 4; ++mt)
            acc[g][mt] = (floatx4){0.f, 0.f, 0.f, 0.f};

    // prologue: A(0)->s0, B(0)->buf0, A(1)->s1   (order matters for vmcnt)
    ISSUE_A(0);
    ISSUE_B(0);
    ISSUE_A(1);

    // 64 K-steps, ring x3 x bbuf x2 -> period 6 unroll; kt in [0,60) in loop.
    for (int t = 0; t < 10; ++t) {
        ITER(0, 2, 0, 1);   // kt = 6t
        ITER(1, 0, 1, 0);   // kt = 6t+1
        ITER(2, 1, 0, 1);   // kt = 6t+2
        ITER(0, 2, 1, 0);   // kt = 6t+3
        ITER(1, 0, 0, 1);   // kt = 6t+4
        ITER(2, 1, 1, 0);   // kt = 6t+5
    }
    ITER(0, 2, 0, 1);       // kt = 60
    ITER(1, 0, 1, 0);       // kt = 61 (issues B62->buf0, A63->s0)
    WAITB(2); ISSUE_B(1); COMPUTE(2, 0);   // kt = 62 (issues B63->buf1)
    WAITB(0); COMPUTE(0, 1);               // kt = 63

    // ------------------------------------------------------------------ epi
    // all 4 gates wave-local.  C/D: col = lane&15, row = (lane>>4)*4 + reg
    const int lrc   = lane & 15;
    const int lquad = lane >> 4;
    const int colg  = bn0 + wN * 16 + lrc;
    const int wrow  = wM * 64;
    float* out_ct = out;
    float* out_ht = out + (size_t)M_DIM * H_DIM;

    const float bf_ = bxf[colg] + bhf[colg];
    const float bi_ = bxi[colg] + bhi[colg];
    const float bo_ = bxo[colg] + bho[colg];
    const float bc_ = bxc[colg] + bhc[colg];

#pragma unroll
    for (int mt = 0; mt < 4; ++mt) {
#pragma unroll
        for (int r = 0; r < 4; ++r) {
            const int row = bm0 + wrow + mt * 16 + lquad * 4 + r;
            const float f    = fast_sigmoid(acc[0][mt][r] + bf_);
            const float ii   = fast_sigmoid(acc[1][mt][r] + bi_);
            const float o    = fast_sigmoid(acc[2][mt][r] + bo_);
            const float ctil = fast_tanh(acc[3][mt][r] + bc_);
            const float cv   = c[(size_t)row * H_DIM + colg];
            const float ctn  = f * cv + ctil * ii;
            const float htn  = fast_tanh(ctn) * o;
            out_ct[(size_t)row * H_DIM + colg] = ctn;
            out_ht[(size_t)row * H_DIM + colg] = htn;
        }
    }
}

extern "C" void kernel_launch(void* const* d_in, const int* in_sizes, int n_in,
                              void* d_out, int out_size, void* d_ws, size_t ws_size,
                              hipStream_t stream) {
    (void)in_sizes; (void)n_in; (void)out_size; (void)ws_size;
    const float* x   = (const float*)d_in[0];
    const float* c   = (const float*)d_in[1];
    const float* h   = (const float*)d_in[2];
    const float* Wxf = (const float*)d_in[3];  const float* bxf = (const float*)d_in[4];
    const float* Whf = (const float*)d_in[5];  const float* bhf = (const float*)d_in[6];
    const float* Wxi = (const float*)d_in[7];  const float* bxi = (const float*)d_in[8];
    const float* Whi = (const float*)d_in[9];  const float* bhi = (const float*)d_in[10];
    const float* Wxo = (const float*)d_in[11]; const float* bxo = (const float*)d_in[12];
    const float* Who = (const float*)d_in[13]; const float* bho = (const float*)d_in[14];
    const float* Wxc = (const float*)d_in[15]; const float* bxc = (const float*)d_in[16];
    const float* Whc = (const float*)d_in[17]; const float* bhc = (const float*)d_in[18];
    float* out = (float*)d_out;
    unsigned short* ws = (unsigned short*)d_ws;   // 32768 chunks x 1 KB = 32 MB

    pack_bf16<<<8192, 256, 0, stream>>>(x, h,
        Wxf, Wxi, Wxo, Wxc, Whf, Whi, Who, Whc, ws);

    lstm_fused_kernel<<<1024, 256, 0, stream>>>(ws, c,
        bxf, bhf, bxi, bhi, bxo, bho, bxc, bhc, out);
}